// Round 11
// baseline (642.505 us; speedup 1.0000x reference)
//
#include <hip/hip_runtime.h>
#include <math.h>

#define BB_ 8
#define LL_ 720
#define NF 321
#define DM 512
#define HH_ 8
#define DH 64
#define DFF 128
#define PRED 336
#define UK 35
#define NLAY 2
#define EPSF 1e-5f
#define BL (BB_*LL_)
#define TJC 72
#define NCH (LL_/TJC)
#define LCH 48
#define NLC (LL_/LCH)

typedef unsigned short ushort;
typedef __attribute__((ext_vector_type(4))) float f32x4;
typedef __attribute__((ext_vector_type(8))) ushort ushort8;
typedef __attribute__((ext_vector_type(4))) ushort ushortx4;

#define KVSEG ((size_t)64*LL_*64)   // one K-or-V pack segment (bh=64 heads)

// ---------- bf16 <-> f32 (raw ushort bits) ----------
__device__ __forceinline__ float b2f(ushort u){
  unsigned int x = ((unsigned int)u) << 16;
  return __builtin_bit_cast(float, x);
}
__device__ __forceinline__ ushort f2b(float f){
  unsigned int x = __builtin_bit_cast(unsigned int, f);
  unsigned int r = x + 0x7fff + ((x >> 16) & 1);   // RNE
  return (ushort)(r >> 16);
}

// ---------- reductions ----------
__device__ __forceinline__ float wredsum(float v){
#pragma unroll
  for (int o=32;o>0;o>>=1) v += __shfl_xor(v,o,64);
  return v;
}
__device__ __forceinline__ float wredmax(float v){
#pragma unroll
  for (int o=32;o>0;o>>=1) v = fmaxf(v,__shfl_xor(v,o,64));
  return v;
}

// ---------- stats partials: one block per (b, n-tile, L-chunk) ----------
__global__ __launch_bounds__(256) void stats3_k(const float* __restrict__ x,
                                                float* __restrict__ pp){
  __shared__ float s1[4][64], s2[4][64];
  int blk = blockIdx.x;                  // b*6*NLC + nt*NLC + lc
  int lc = blk % NLC; int r = blk / NLC;
  int nt = r % 6; int b = r / 6;
  int nl = threadIdx.x & 63, lg = threadIdx.x >> 6;
  int n = nt*64 + nl;
  float sum=0.f, ss=0.f;
  if (n < NF){
    const float* xp = x + ((size_t)b*LL_ + lc*LCH)*NF + n;
    for (int l=lg; l<LCH; l+=4){ float v = xp[(size_t)l*NF]; sum += v; ss = fmaf(v,v,ss); }
  }
  s1[lg][nl]=sum; s2[lg][nl]=ss;
  __syncthreads();
  if (lg==0){
    float S = s1[0][nl]+s1[1][nl]+s1[2][nl]+s1[3][nl];
    float Q = s2[0][nl]+s2[1][nl]+s2[2][nl]+s2[3][nl];
    pp[(size_t)blk*128 + nl]      = S;
    pp[(size_t)blk*128 + 64 + nl] = Q;
  }
}

// ---------- stats combine: one block per (b, n-tile) ----------
__global__ __launch_bounds__(64) void statsc_k(const float* __restrict__ pp,
                                               float* __restrict__ mean,
                                               float* __restrict__ stdv,
                                               float* __restrict__ rstd){
  int bn6 = blockIdx.x;                  // b*6 + nt
  int nl = threadIdx.x;
  int nt = bn6 % 6, b = bn6 / 6;
  int n = nt*64 + nl;
  if (n >= NF) return;
  float S=0.f, Q=0.f;
#pragma unroll
  for (int lc=0; lc<NLC; ++lc){
    size_t base = ((size_t)(b*6+nt)*NLC + lc)*128;
    S += pp[base + nl];
    Q += pp[base + 64 + nl];
  }
  float mu = S*(1.f/LL_);
  float var = fmaxf((Q - S*mu)*(1.f/(LL_-1)), 0.f);
  float sd = sqrtf(var) + EPSF;
  int bn = b*NF+n;
  mean[bn]=mu; stdv[bn]=sd; rstd[bn]=1.f/sd;
}

// ---------- normalized input -> bf16, K padded to 352 ----------
#define KPE 352
__global__ __launch_bounds__(256) void xnorm_k(const float* __restrict__ x,
                                               const float* __restrict__ mean,
                                               const float* __restrict__ rstd,
                                               ushort* __restrict__ xn){
  int idx = blockIdx.x*256 + threadIdx.x;
  if (idx >= BL*KPE) return;
  int c = idx % KPE; int bl = idx / KPE; int b = bl / LL_;
  float v = 0.f;
  if (c < NF) v = (x[(size_t)bl*NF + c] - mean[b*NF+c]) * rstd[b*NF+c];
  xn[idx] = f2b(v);
}

// ---------- weight transpose+convert mega-kernel ----------
struct TDesc { const float* in; ushort* out; int N, K, Npad, Kpad, nbx, blk0, ilv; };
struct TPack { TDesc d[17]; int n; };
__global__ __launch_bounds__(256) void transpose_k(TPack p){
  __shared__ float tile[32][33];
  int blk = blockIdx.x;
  int di = 0;
  while (di+1 < p.n && p.d[di+1].blk0 <= blk) ++di;
  TDesc D = p.d[di];
  int rel = blk - D.blk0;
  int bx = rel % D.nbx, by = rel / D.nbx;
  int k0 = bx*32, n0 = by*32;
  int t = threadIdx.x; int tx = t & 31, ty = t >> 5;
#pragma unroll
  for (int i=0;i<4;++i){
    int k = k0+ty+8*i, n = n0+tx;
    float v = (k < D.K && n < D.N) ? D.in[(size_t)k*D.N + n] : 0.f;
    tile[ty+8*i][tx] = v;
  }
  __syncthreads();
#pragma unroll
  for (int i=0;i<4;++i){
    int n = n0+ty+8*i, k = k0+tx;
    if (n < D.Npad && k < D.Kpad){
      int outn = D.ilv ? (2*n + (D.ilv-1)) : n;
      D.out[(size_t)outn*D.Kpad + k] = f2b(tile[tx][ty+8*i]);
    }
  }
}

// ---------- fused bias packing (qkv + interleaved out/gate) ----------
__global__ __launch_bounds__(256) void pack_bias_k(const float* __restrict__ bq,
                                                   const float* __restrict__ bk,
                                                   const float* __restrict__ bv,
                                                   const float* __restrict__ bo2,
                                                   const float* __restrict__ bg,
                                                   float* __restrict__ bqkv,
                                                   float* __restrict__ bog){
  int t = blockIdx.x*256 + threadIdx.x;
  if (t < 2*1536){
    int l = t/1536, c = t%1536;
    float v = c<512 ? bq[l*512+c] : (c<1024 ? bk[l*512+c-512] : bv[l*512+c-1024]);
    bqkv[t] = v;
  }
  if (t < 2*672){
    int l = t/672, c = t%672;
    int p = c>>1;
    bog[t] = (c&1) ? bg[l*336+p] : bo2[l*336+p];
  }
}

// ---------- bf16 MFMA GEMM: C[M,N] = A[M,K] @ Bt[N,K]^T + bias ----------
// flags: 1=relu, 2=bf16-only out, 8=qkv mode (q fp32; K->kR, V->vp bf16 row packs),
//        16=gate epilogue y[row][col/2] (+)= t1*sigmoid(t2), 32=gate accumulate
__global__ __launch_bounds__(256) void gemm_k(
    const ushort* __restrict__ A, const ushort* __restrict__ Bt,
    const float* __restrict__ bias, void* __restrict__ Cout,
    ushort* __restrict__ kvp,
    int N, int K, int flags)
{
  __shared__ ushort As[128*32];
  __shared__ ushort Bs[128*32];
  const int t = threadIdx.x;
  const int bm = blockIdx.y << 7, bn = blockIdx.x << 7;
  const int lane = t & 63, wid = t >> 6;
  const int wm = (wid >> 1) << 6, wn = (wid & 1) << 6;
  const int fr = lane & 15, kg = lane >> 4;

  f32x4 acc[4][4];
#pragma unroll
  for (int i=0;i<4;++i)
#pragma unroll
    for (int j=0;j<4;++j) acc[i][j] = (f32x4){0.f,0.f,0.f,0.f};

  const int rA0 = t >> 2,        qA0 = t & 3;
  const int rA1 = (t+256) >> 2;
  const size_t aOff0 = (size_t)(bm + rA0)*K + qA0*8;
  const size_t aOff1 = (size_t)(bm + rA1)*K + qA0*8;
  const size_t bOff0 = (size_t)(bn + rA0)*K + qA0*8;
  const size_t bOff1 = (size_t)(bn + rA1)*K + qA0*8;
  const int lA0 = (rA0<<5) + ((qA0 ^ ((rA0>>1)&3))<<3);
  const int lA1 = (rA1<<5) + ((qA0 ^ ((rA1>>1)&3))<<3);

  for (int k0=0; k0<K; k0+=32){
    ushort8 va0 = *(const ushort8*)(A  + aOff0 + k0);
    ushort8 va1 = *(const ushort8*)(A  + aOff1 + k0);
    ushort8 vb0 = *(const ushort8*)(Bt + bOff0 + k0);
    ushort8 vb1 = *(const ushort8*)(Bt + bOff1 + k0);
    *(ushort8*)&As[lA0] = va0;
    *(ushort8*)&As[lA1] = va1;
    *(ushort8*)&Bs[lA0] = vb0;
    *(ushort8*)&Bs[lA1] = vb1;
    __syncthreads();
    ushort8 af[4], bfr[4];
#pragma unroll
    for (int i=0;i<4;++i){
      int ra = wm + (i<<4) + fr;
      af[i]  = *(const ushort8*)&As[(ra<<5) + ((kg ^ ((ra>>1)&3))<<3)];
      int rb = wn + (i<<4) + fr;
      bfr[i] = *(const ushort8*)&Bs[(rb<<5) + ((kg ^ ((rb>>1)&3))<<3)];
    }
#pragma unroll
    for (int i=0;i<4;++i)
#pragma unroll
      for (int j=0;j<4;++j)
        asm("v_mfma_f32_16x16x32_bf16 %0, %1, %2, %0"
            : "+v"(acc[i][j]) : "v"(af[i]), "v"(bfr[j]));
    __syncthreads();
  }

  const int colBase = bn + wn + fr;
  const int rowBase = bm + wm + (kg << 2);

  if (flags & 16){
#pragma unroll
    for (int j=0;j<4;++j){
      int col = colBase + (j<<4);
      if (col >= N) continue;               // 672 is 16-aligned: wave-uniform
      float bv = bias[col];
#pragma unroll
      for (int i=0;i<4;++i){
        int row0 = rowBase + (i<<4);
#pragma unroll
        for (int r=0;r<4;++r){
          float v = acc[i][j][r] + bv;
          float o = __shfl_xor(v, 1, 64);   // partner (t2 for even lanes)
          if ((lane & 1) == 0){
            float val = v * (1.f/(1.f+__expf(-o)));
            size_t yi = (size_t)(row0+r)*PRED + (col>>1);
            float* yp = (float*)Cout;
            yp[yi] = (flags & 32) ? (yp[yi] + val) : val;
          }
        }
      }
    }
    return;
  }

#pragma unroll
  for (int j=0;j<4;++j){
    int col = colBase + (j<<4);
    if (col >= N) continue;
    float bv = bias[col];
#pragma unroll
    for (int i=0;i<4;++i){
      int row0 = rowBase + (i<<4);
#pragma unroll
      for (int r=0;r<4;++r){
        float v = acc[i][j][r] + bv;
        if (flags & 1) v = fmaxf(v, 0.f);
        int row = row0 + r;
        size_t idx = (size_t)row*N + col;
        if (flags & 2) ((ushort*)Cout)[idx] = f2b(v);
        else if (flags & 8){
          if (col < 512) ((float*)Cout)[idx] = v;
          else {
            int hh = (col >> 6) & 7;
            int dd = col & 63;
            int bb = row / LL_; int jr = row - bb*LL_;
            ushort bfv = f2b(v);
            if (col < 1024)   // K rows: kR [bh][L][d]
              kvp[((size_t)(bb*8+hh)*LL_ + jr)*64 + dd] = bfv;
            else              // V rows: [bh][L][d]
              kvp[KVSEG + ((size_t)(bb*8+hh)*LL_ + jr)*64 + dd] = bfv;
          }
        } else {
          ((float*)Cout)[idx] = v;
        }
      }
    }
  }
}

// ---------- sampled-QK + M score: block = (bh, 8 l's); 32-lane groups ----------
__global__ __launch_bounds__(256) void msc2_k(const float* __restrict__ qkv,
                                              const ushort* __restrict__ kR,
                                              const int* __restrict__ samp,
                                              float* __restrict__ Mb){
  __shared__ float sq[8][64];
  __shared__ int sidx[8][UK];
  int blk = blockIdx.x;          // bh*90 + l8
  int l8 = blk % 90; int bh = blk / 90;
  int b = bh >> 3, h = bh & 7; int l0 = l8*8;
  int t = threadIdx.x;
  for (int i=t; i<8*64; i+=256){
    int u = i>>6, d = i&63;
    sq[u][d] = qkv[(size_t)(b*LL_ + l0+u)*1536 + h*64 + d];
  }
  for (int i=t; i<8*UK; i+=256)
    sidx[i/UK][i%UK] = samp[(l0 + i/UK)*UK + i%UK];
  __syncthreads();
  int g = t >> 5, gl = t & 31;
  bool has1 = gl < (UK - 32);    // gl<3 handles samples 32..34
  int j0 = sidx[g][gl];
  int j1 = has1 ? sidx[g][gl+32] : j0;
  const ushort8* k0 = (const ushort8*)(kR + ((size_t)bh*LL_ + j0)*64);
  const ushort8* k1 = (const ushort8*)(kR + ((size_t)bh*LL_ + j1)*64);
  const float* qu = sq[g];
  float a0 = 0.f, a1 = 0.f;
#pragma unroll
  for (int d8=0; d8<8; ++d8){
    ushort8 x0 = k0[d8];
    ushort8 x1 = k1[d8];
#pragma unroll
    for (int e=0;e<8;++e){
      float q = qu[d8*8+e];
      a0 = fmaf(q, b2f(x0[e]), a0);
      a1 = fmaf(q, b2f(x1[e]), a1);
    }
  }
  float mx = has1 ? fmaxf(a0, a1) : a0;
  float sm = has1 ? (a0 + a1) : a0;
#pragma unroll
  for (int o=16;o>0;o>>=1){
    mx = fmaxf(mx, __shfl_xor(mx, o, 32));
    sm += __shfl_xor(sm, o, 32);
  }
  if (gl == 0) Mb[(size_t)bh*LL_ + l0 + g] = mx - sm*(1.f/LL_);
}

// ---------- top-U per (b,h): one wave, shuffle-only; also builds sel map ----------
__global__ __launch_bounds__(64) void topk2_k(const float* __restrict__ Mb,
                                              int* __restrict__ mtop,
                                              int* __restrict__ sel){
  int bh = blockIdx.x; int lane = threadIdx.x;
  const float* mp = Mb + (size_t)bh*LL_;
  for (int j=lane; j<LL_; j+=64) sel[(size_t)bh*LL_ + j] = -1;
  float v[12]; int vi[12];
#pragma unroll
  for (int i=0;i<12;++i){
    int j = lane + i*64;
    bool ok = j < LL_;
    v[i] = ok ? mp[j] : -INFINITY;
    vi[i] = ok ? j : (LL_ + i);
  }
  for (int it=0; it<UK; ++it){
    float best = v[0]; int bi = vi[0]; int bslot = 0;
#pragma unroll
    for (int i=1;i<12;++i){
      if (v[i] > best || (v[i]==best && vi[i] < bi)){ best=v[i]; bi=vi[i]; bslot=i; }
    }
    float gb = best; int gi = bi;
#pragma unroll
    for (int o=32;o>0;o>>=1){
      float ov = __shfl_xor(gb,o,64); int oi = __shfl_xor(gi,o,64);
      if (ov > gb || (ov==gb && oi < gi)){ gb=ov; gi=oi; }
    }
    if (lane==0){
      mtop[(size_t)bh*UK + it] = gi;
      sel[(size_t)bh*LL_ + gi] = it;
    }
    if (bi == gi){
#pragma unroll
      for (int i=0;i<12;++i) if (i==bslot) v[i] = -INFINITY;
    }
  }
}

// ---------- combine per-chunk V sums -> v mean ----------
__global__ __launch_bounds__(256) void vmnc_k(const float* __restrict__ pvs,
                                              float* __restrict__ vmn){
  int idx = blockIdx.x*256 + threadIdx.x;   // < 64*64
  if (idx >= 64*64) return;
  int bh = idx >> 6, d = idx & 63;
  float s = 0.f;
#pragma unroll
  for (int ch=0; ch<NCH; ++ch) s += pvs[((size_t)bh*NCH + ch)*64 + d];
  vmn[idx] = s*(1.f/LL_);
}

// ---------- chunked attention partials: one block per (b,h,chunk) ----------
__global__ __launch_bounds__(256) void attn4_k(const float* __restrict__ qkv,
                                               const ushort* __restrict__ kR,
                                               const ushort* __restrict__ vp,
                                               const int* __restrict__ mtop,
                                               float* __restrict__ pacc,
                                               float* __restrict__ pm,
                                               float* __restrict__ pl,
                                               float* __restrict__ pvs){
  __shared__ ushort skT[64][TJC];    // K^T chunk
  __shared__ ushort sv[TJC][64];     // V chunk
  __shared__ float  sq[UK][64];
  __shared__ float  sc[UK][TJC];
  __shared__ float  part[4][64];
  int blk = blockIdx.x;
  int ch = blk % NCH; int bh = blk / NCH;
  int b = bh >> 3, h = bh & 7; int t0 = ch*TJC;
  int t = threadIdx.x, lane = t & 63, wid = t >> 6;
  for (int idx=t; idx<TJC*8; idx+=256){
    int jj = idx>>3, c8 = idx&7;
    ushort8 kk = *(const ushort8*)(kR + ((size_t)bh*LL_ + t0+jj)*64 + c8*8);
#pragma unroll
    for (int e=0;e<8;++e) skT[c8*8+e][jj] = kk[e];
  }
  for (int idx=t; idx<TJC*8; idx+=256){
    int jj = idx>>3, c8 = idx&7;
    *(ushort8*)&sv[jj][c8*8] =
      *(const ushort8*)(vp + ((size_t)bh*LL_ + t0+jj)*64 + c8*8);
  }
  for (int idx=t; idx<UK*64; idx+=256){
    int u = idx>>6, d = idx&63;
    int row = mtop[bh*UK + u];
    sq[u][d] = qkv[(size_t)(b*LL_ + row)*1536 + h*64 + d];
  }
  __syncthreads();
  {
    int d = t & 63, q = t >> 6;
    float s = 0.f;
    for (int jj=q; jj<TJC; jj+=4) s += b2f(sv[jj][d]);
    part[q][d] = s;
  }
  for (int idx=t; idx<UK*(TJC/8); idx+=256){
    int u = idx/(TJC/8), jb = idx%(TJC/8);
    float dot[8] = {0.f,0.f,0.f,0.f,0.f,0.f,0.f,0.f};
    const float* qu = sq[u];
#pragma unroll
    for (int d=0; d<64; ++d){
      ushort8 kk = *(const ushort8*)&skT[d][jb*8];
      float qv = qu[d];
#pragma unroll
      for (int e=0;e<8;++e) dot[e] = fmaf(qv, b2f(kk[e]), dot[e]);
    }
#pragma unroll
    for (int e=0;e<8;++e) sc[u][jb*8+e] = dot[e]*0.125f;
  }
  __syncthreads();
  if (t < 64)
    pvs[((size_t)bh*NCH + ch)*64 + t] = part[0][t]+part[1][t]+part[2][t]+part[3][t];
  for (int u=wid; u<UK; u+=4){
    float v0 = sc[u][lane];
    float v1 = (lane < TJC-64) ? sc[u][64+lane] : -3.0e38f;
    float mx = wredmax(fmaxf(v0,v1));
    float e0 = __expf(v0-mx);
    float e1 = (lane < TJC-64) ? __expf(v1-mx) : 0.f;
    sc[u][lane] = e0;
    if (lane < TJC-64) sc[u][64+lane] = e1;
    float s = wredsum(e0+e1);
    if (lane==0){
      pm[((size_t)bh*NCH+ch)*UK + u] = mx;
      pl[((size_t)bh*NCH+ch)*UK + u] = s;
    }
  }
  __syncthreads();
  for (int idx=t; idx<UK*64; idx+=256){
    int u = idx>>6, d = idx&63;
    const float* scu = sc[u];
    float a = 0.f;
#pragma unroll 8
    for (int jj=0; jj<TJC; ++jj) a = fmaf(scu[jj], b2f(sv[jj][d]), a);
    pacc[(((size_t)bh*NCH+ch)*UK + u)*64 + d] = a;
  }
}

// ---------- write ctx: vmean broadcast or combined attention row ----------
__global__ __launch_bounds__(256) void ctxw_k(const float* __restrict__ pacc,
                                              const float* __restrict__ pm,
                                              const float* __restrict__ pl,
                                              const float* __restrict__ vmn,
                                              const int* __restrict__ sel,
                                              ushort* __restrict__ ctx){
  int bl = blockIdx.x;                // b*LL_ + l
  int b = bl / LL_; int l = bl - b*LL_;
  int t = threadIdx.x;
  for (int c=t; c<DM; c+=256){
    int h = c >> 6, d = c & 63;
    int bh = b*8 + h;
    int u = sel[(size_t)bh*LL_ + l];
    float val;
    if (u < 0){
      val = vmn[bh*64 + d];
    } else {
      float pmv[NCH];
      float M = -3.0e38f;
#pragma unroll
      for (int ch=0; ch<NCH; ++ch){
        pmv[ch] = pm[((size_t)bh*NCH+ch)*UK + u];
        M = fmaxf(M, pmv[ch]);
      }
      float L = 0.f, A = 0.f;
#pragma unroll
      for (int ch=0; ch<NCH; ++ch){
        float w = __expf(pmv[ch] - M);
        L += w * pl[((size_t)bh*NCH+ch)*UK + u];
        A += w * pacc[(((size_t)bh*NCH+ch)*UK + u)*64 + d];
      }
      val = A / L;
    }
    ctx[(size_t)bl*DM + c] = f2b(val);
  }
}

// ---------- LN(a - s): bf16 a, fp32 s, single-pass, bf16 out ----------
__global__ __launch_bounds__(256) void subln_k(const ushort* __restrict__ a,
                                               const float* __restrict__ s,
                                               const float* __restrict__ g,
                                               const float* __restrict__ be,
                                               ushort* __restrict__ obf){
  __shared__ float red[8];
  int row = blockIdx.x;
  size_t base = (size_t)row * DM;
  int t = threadIdx.x;
  int lane = t & 63, wid = t >> 6;
  float e0 = b2f(a[base+t])     - s[base+t];
  float e1 = b2f(a[base+t+256]) - s[base+t+256];
  float s1 = e0+e1;
  float s2 = e0*e0 + e1*e1;
#pragma unroll
  for (int o=32;o>0;o>>=1){
    s1 += __shfl_xor(s1,o,64);
    s2 += __shfl_xor(s2,o,64);
  }
  if (lane==0){ red[wid]=s1; red[4+wid]=s2; }
  __syncthreads();
  float S = red[0]+red[1]+red[2]+red[3];
  float Q = red[4]+red[5]+red[6]+red[7];
  float mu = S*(1.f/DM);
  float var = fmaxf(Q*(1.f/DM) - mu*mu, 0.f);
  float rs = rsqrtf(var + EPSF);
  obf[base+t]     = f2b((e0-mu)*rs*g[t]     + be[t]);
  obf[base+t+256] = f2b((e1-mu)*rs*g[t+256] + be[t+256]);
}

// ---------- final: LDS-tiled transpose, out[b,p,n] = y[b,n,p]*std + mean ----------
__global__ __launch_bounds__(256) void final2_k(const float* __restrict__ y,
                                                const float* __restrict__ stdv,
                                                const float* __restrict__ mean,
                                                float* __restrict__ out){
  __shared__ float tile[32][33];
  int n0 = blockIdx.x*32, p0 = blockIdx.y*32, b = blockIdx.z;
  int tx = threadIdx.x & 31, ty = threadIdx.x >> 5;
  for (int i=ty; i<32; i+=8){
    int n = n0+i, p = p0+tx;
    tile[i][tx] = (n<NF && p<PRED) ? y[((size_t)b*LL_+n)*PRED + p] : 0.f;
  }
  __syncthreads();
  for (int i=ty; i<32; i+=8){
    int p = p0+i, n = n0+tx;
    if (p<PRED && n<NF)
      out[((size_t)b*PRED + p)*NF + n] = tile[tx][i]*stdv[b*NF+n] + mean[b*NF+n];
  }
}

// ---------------- host ----------------
extern "C" void kernel_launch(void* const* d_in, const int* in_sizes, int n_in,
                              void* d_out, int out_size, void* d_ws, size_t ws_size,
                              hipStream_t stream){
  const float* x_enc = (const float*)d_in[0];
  const int*   samp  = (const int*)  d_in[1];
  const float* embw  = (const float*)d_in[2];
  const float* embb  = (const float*)d_in[3];
  const float* wq    = (const float*)d_in[4];
  const float* bq    = (const float*)d_in[5];
  const float* wk    = (const float*)d_in[6];
  const float* bk    = (const float*)d_in[7];
  const float* wv    = (const float*)d_in[8];
  const float* bv    = (const float*)d_in[9];
  const float* wo    = (const float*)d_in[10];
  const float* bo    = (const float*)d_in[11];
  const float* ln1g  = (const float*)d_in[12];
  const float* ln1b  = (const float*)d_in[13];
  const float* w1    = (const float*)d_in[14];
  const float* b1    = (const float*)d_in[15];
  const float* w2    = (const float*)d_in[16];
  const float* b2    = (const float*)d_in[17];
  const float* ln2g  = (const float*)d_in[18];
  const float* ln2b  = (const float*)d_in[19];
  const float* wout  = (const float*)d_in[20];
  const float* boutp = (const float*)d_in[21];
  const float* wg    = (const float*)d_in[22];
  const float* bg    = (const float*)d_in[23];
  float* out = (float*)d_out;

  char* wsb = (char*)d_ws;
  size_t off = 0;
  auto alloc = [&](size_t bytes)->void*{
    void* p = wsb + off; off += (bytes + 255) & ~(size_t)255; return p;
  };
  float* mean  = (float*)alloc((size_t)BB_*NF*4);
  float* stdv  = (float*)alloc((size_t)BB_*NF*4);
  float* rstd  = (float*)alloc((size_t)BB_*NF*4);
  float* pp    = (float*)alloc((size_t)BB_*6*NLC*128*4);
  float* bqkv  = (float*)alloc(2*1536*4);
  float* bog   = (float*)alloc(2*672*4);
  ushort* xn     = (ushort*)alloc((size_t)BL*KPE*2);
  ushort* we_t   = (ushort*)alloc((size_t)512*KPE*2);
  ushort* wqkv_t = (ushort*)alloc((size_t)2*1536*512*2);
  ushort* wo_t   = (ushort*)alloc((size_t)2*512*512*2);
  ushort* w1_t   = (ushort*)alloc((size_t)2*128*512*2);
  ushort* w2_t   = (ushort*)alloc((size_t)2*512*128*2);
  ushort* wog_t  = (ushort*)alloc((size_t)2*768*512*2);
  ushort* h_bf   = (ushort*)alloc((size_t)BL*DM*2);
  ushort* hx_bf  = (ushort*)alloc((size_t)BL*DM*2);
  ushort* ctx_bf = (ushort*)alloc((size_t)BL*DM*2);
  ushort* ff1_bf = (ushort*)alloc((size_t)BL*DFF*2);
  ushort* kvpack = (ushort*)alloc(2*KVSEG*2);
  float* qkv = (float*)alloc((size_t)BL*1536*4);
  float* tmp = (float*)alloc((size_t)BL*DM*4);
  float* y   = (float*)alloc((size_t)BL*PRED*4);
  float* Mb  = (float*)alloc((size_t)BB_*HH_*LL_*4);
  int*  mtop = (int*)  alloc((size_t)BB_*HH_*UK*4);
  int*  sel  = (int*)  alloc((size_t)BB_*HH_*LL_*4);
  float* vmn = (float*)alloc((size_t)BB_*HH_*DH*4);
  float* pacc = (float*)alloc((size_t)64*NCH*UK*64*4);
  float* pm   = (float*)alloc((size_t)64*NCH*UK*4);
  float* pl   = (float*)alloc((size_t)64*NCH*UK*4);
  float* pvs  = (float*)alloc((size_t)64*NCH*64*4);
  if (off > ws_size) return;
  ushort* kRp   = kvpack;
  ushort* vpack = kvpack + KVSEG;

  stats3_k<<<BB_*6*NLC, 256, 0, stream>>>(x_enc, pp);
  statsc_k<<<BB_*6, 64, 0, stream>>>(pp, mean, stdv, rstd);
  xnorm_k<<<(BL*KPE+255)/256, 256, 0, stream>>>(x_enc, mean, rstd, xn);

  TPack tp; int blk = 0; int di = 0;
  auto addT = [&](const float* in, ushort* o, int N, int K, int Npad, int Kpad, int ilv){
    TDesc& d = tp.d[di++]; d.in=in; d.out=o; d.N=N; d.K=K; d.Npad=Npad; d.Kpad=Kpad; d.ilv=ilv;
    d.nbx = (Kpad+31)/32; d.blk0 = blk; blk += d.nbx * ((Npad+31)/32);
  };
  addT(embw, we_t, 512, NF, 512, KPE, 0);
  for (int l=0;l<NLAY;++l){
    addT(wq + (size_t)l*262144, wqkv_t + (size_t)l*786432,            512,512,512,512,0);
    addT(wk + (size_t)l*262144, wqkv_t + (size_t)l*786432 + 262144,   512,512,512,512,0);
    addT(wv + (size_t)l*262144, wqkv_t + (size_t)l*786432 + 524288,   512,512,512,512,0);
    addT(wo + (size_t)l*262144, wo_t   + (size_t)l*262144,            512,512,512,512,0);
    addT(w1 + (size_t)l*65536,  w1_t   + (size_t)l*65536,             128,512,128,512,0);
    addT(w2 + (size_t)l*65536,  w2_t   + (size_t)l*65536,             512,128,512,128,0);
    addT(wout + (size_t)l*172032, wog_t + (size_t)l*393216,           336,512,384,512,1);
    addT(wg   + (size_t)l*172032, wog_t + (size_t)l*393216,           336,512,384,512,2);
  }
  tp.n = di;
  transpose_k<<<blk, 256, 0, stream>>>(tp);
  pack_bias_k<<<12, 256, 0, stream>>>(bq, bk, bv, boutp, bg, bqkv, bog);

  // embed: h = xn @ embw + embb  (bf16 out)
  gemm_k<<<dim3(4,45), 256, 0, stream>>>(xn, we_t, embb, h_bf, nullptr,
                                         512, KPE, 2);

  for (int l=0;l<NLAY;++l){
    gemm_k<<<dim3(12,45), 256, 0, stream>>>(h_bf, wqkv_t + (size_t)l*786432,
                                            bqkv + l*1536, qkv, kvpack,
                                            1536, 512, 8);
    msc2_k<<<64*90, 256, 0, stream>>>(qkv, kRp, samp, Mb);
    topk2_k<<<BB_*HH_, 64, 0, stream>>>(Mb, mtop, sel);
    attn4_k<<<64*NCH, 256, 0, stream>>>(qkv, kRp, vpack, mtop, pacc, pm, pl, pvs);
    vmnc_k<<<16, 256, 0, stream>>>(pvs, vmn);
    ctxw_k<<<BL, 256, 0, stream>>>(pacc, pm, pl, vmn, sel, ctx_bf);
    gemm_k<<<dim3(4,45), 256, 0, stream>>>(ctx_bf, wo_t + (size_t)l*262144,
                                           bo + l*512, tmp, nullptr,
                                           512, 512, 0);
    subln_k<<<BL, 256, 0, stream>>>(h_bf, tmp, ln1g + l*512, ln1b + l*512, hx_bf);
    gemm_k<<<dim3(1,45), 256, 0, stream>>>(hx_bf, w1_t + (size_t)l*65536,
                                           b1 + l*128, ff1_bf, nullptr,
                                           128, 512, 3);
    gemm_k<<<dim3(4,45), 256, 0, stream>>>(ff1_bf, w2_t + (size_t)l*65536,
                                           b2 + l*512, tmp, nullptr,
                                           512, 128, 0);
    subln_k<<<BL, 256, 0, stream>>>(hx_bf, tmp, ln2g + l*512, ln2b + l*512, h_bf);
    gemm_k<<<dim3(6,45), 256, 0, stream>>>(h_bf, wog_t + (size_t)l*393216,
                                           bog + l*672, y, nullptr,
                                           672, 512, 16 | (l ? 32 : 0));
  }
  final2_k<<<dim3((NF+31)/32,(PRED+31)/32,BB_), 256, 0, stream>>>(y, stdv, mean, out);
}

// Round 12
// 585.943 us; speedup vs baseline: 1.0965x; 1.0965x over previous
//
#include <hip/hip_runtime.h>
#include <math.h>

#define BB_ 8
#define LL_ 720
#define NF 321
#define DM 512
#define HH_ 8
#define DH 64
#define DFF 128
#define PRED 336
#define UK 35
#define NLAY 2
#define EPSF 1e-5f
#define BL (BB_*LL_)
#define TJC 72
#define NCH (LL_/TJC)
#define LCH 48
#define NLC (LL_/LCH)

typedef unsigned short ushort;
typedef __attribute__((ext_vector_type(4))) float f32x4;
typedef __attribute__((ext_vector_type(8))) ushort ushort8;
typedef __attribute__((ext_vector_type(4))) ushort ushortx4;

#define KVSEG ((size_t)64*LL_*64)   // one K-or-V pack segment (bh=64 heads)

// ---------- bf16 <-> f32 (raw ushort bits) ----------
__device__ __forceinline__ float b2f(ushort u){
  unsigned int x = ((unsigned int)u) << 16;
  return __builtin_bit_cast(float, x);
}
__device__ __forceinline__ ushort f2b(float f){
  unsigned int x = __builtin_bit_cast(unsigned int, f);
  unsigned int r = x + 0x7fff + ((x >> 16) & 1);   // RNE
  return (ushort)(r >> 16);
}

// ---------- reductions ----------
__device__ __forceinline__ float wredsum(float v){
#pragma unroll
  for (int o=32;o>0;o>>=1) v += __shfl_xor(v,o,64);
  return v;
}
__device__ __forceinline__ float wredmax(float v){
#pragma unroll
  for (int o=32;o>0;o>>=1) v = fmaxf(v,__shfl_xor(v,o,64));
  return v;
}

// ---------- stats partials: one block per (b, n-tile, L-chunk) ----------
__global__ __launch_bounds__(256) void stats3_k(const float* __restrict__ x,
                                                float* __restrict__ pp){
  __shared__ float s1[4][64], s2[4][64];
  int blk = blockIdx.x;                  // b*6*NLC + nt*NLC + lc
  int lc = blk % NLC; int r = blk / NLC;
  int nt = r % 6; int b = r / 6;
  int nl = threadIdx.x & 63, lg = threadIdx.x >> 6;
  int n = nt*64 + nl;
  float sum=0.f, ss=0.f;
  if (n < NF){
    const float* xp = x + ((size_t)b*LL_ + lc*LCH)*NF + n;
    for (int l=lg; l<LCH; l+=4){ float v = xp[(size_t)l*NF]; sum += v; ss = fmaf(v,v,ss); }
  }
  s1[lg][nl]=sum; s2[lg][nl]=ss;
  __syncthreads();
  if (lg==0){
    float S = s1[0][nl]+s1[1][nl]+s1[2][nl]+s1[3][nl];
    float Q = s2[0][nl]+s2[1][nl]+s2[2][nl]+s2[3][nl];
    pp[(size_t)blk*128 + nl]      = S;
    pp[(size_t)blk*128 + 64 + nl] = Q;
  }
}

// ---------- stats combine: one block per (b, n-tile) ----------
__global__ __launch_bounds__(64) void statsc_k(const float* __restrict__ pp,
                                               float* __restrict__ mean,
                                               float* __restrict__ stdv,
                                               float* __restrict__ rstd){
  int bn6 = blockIdx.x;                  // b*6 + nt
  int nl = threadIdx.x;
  int nt = bn6 % 6, b = bn6 / 6;
  int n = nt*64 + nl;
  if (n >= NF) return;
  float S=0.f, Q=0.f;
#pragma unroll
  for (int lc=0; lc<NLC; ++lc){
    size_t base = ((size_t)(b*6+nt)*NLC + lc)*128;
    S += pp[base + nl];
    Q += pp[base + 64 + nl];
  }
  float mu = S*(1.f/LL_);
  float var = fmaxf((Q - S*mu)*(1.f/(LL_-1)), 0.f);
  float sd = sqrtf(var) + EPSF;
  int bn = b*NF+n;
  mean[bn]=mu; stdv[bn]=sd; rstd[bn]=1.f/sd;
}

// ---------- normalized input -> bf16, K padded to 352 ----------
#define KPE 352
__global__ __launch_bounds__(256) void xnorm_k(const float* __restrict__ x,
                                               const float* __restrict__ mean,
                                               const float* __restrict__ rstd,
                                               ushort* __restrict__ xn){
  int idx = blockIdx.x*256 + threadIdx.x;
  if (idx >= BL*KPE) return;
  int c = idx % KPE; int bl = idx / KPE; int b = bl / LL_;
  float v = 0.f;
  if (c < NF) v = (x[(size_t)bl*NF + c] - mean[b*NF+c]) * rstd[b*NF+c];
  xn[idx] = f2b(v);
}

// ---------- weight transpose+convert mega-kernel ----------
struct TDesc { const float* in; ushort* out; int N, K, Npad, Kpad, nbx, blk0, ilv; };
struct TPack { TDesc d[17]; int n; };
__global__ __launch_bounds__(256) void transpose_k(TPack p){
  __shared__ float tile[32][33];
  int blk = blockIdx.x;
  int di = 0;
  while (di+1 < p.n && p.d[di+1].blk0 <= blk) ++di;
  TDesc D = p.d[di];
  int rel = blk - D.blk0;
  int bx = rel % D.nbx, by = rel / D.nbx;
  int k0 = bx*32, n0 = by*32;
  int t = threadIdx.x; int tx = t & 31, ty = t >> 5;
#pragma unroll
  for (int i=0;i<4;++i){
    int k = k0+ty+8*i, n = n0+tx;
    float v = (k < D.K && n < D.N) ? D.in[(size_t)k*D.N + n] : 0.f;
    tile[ty+8*i][tx] = v;
  }
  __syncthreads();
#pragma unroll
  for (int i=0;i<4;++i){
    int n = n0+ty+8*i, k = k0+tx;
    if (n < D.Npad && k < D.Kpad){
      int outn = D.ilv ? (2*n + (D.ilv-1)) : n;
      D.out[(size_t)outn*D.Kpad + k] = f2b(tile[tx][ty+8*i]);
    }
  }
}

// ---------- fused bias packing (qkv + interleaved out/gate) ----------
__global__ __launch_bounds__(256) void pack_bias_k(const float* __restrict__ bq,
                                                   const float* __restrict__ bk,
                                                   const float* __restrict__ bv,
                                                   const float* __restrict__ bo2,
                                                   const float* __restrict__ bg,
                                                   float* __restrict__ bqkv,
                                                   float* __restrict__ bog){
  int t = blockIdx.x*256 + threadIdx.x;
  if (t < 2*1536){
    int l = t/1536, c = t%1536;
    float v = c<512 ? bq[l*512+c] : (c<1024 ? bk[l*512+c-512] : bv[l*512+c-1024]);
    bqkv[t] = v;
  }
  if (t < 2*672){
    int l = t/672, c = t%672;
    int p = c>>1;
    bog[t] = (c&1) ? bg[l*336+p] : bo2[l*336+p];
  }
}

// ---------- bf16 MFMA GEMM: C[M,N] = A[M,K] @ Bt[N,K]^T + bias ----------
// flags: 1=relu, 2=bf16-only out, 8=qkv mode (q fp32; K->kR, V->vp bf16 row packs),
//        16=gate epilogue y[row][col/2] (+)= t1*sigmoid(t2), 32=gate accumulate
__global__ __launch_bounds__(256) void gemm_k(
    const ushort* __restrict__ A, const ushort* __restrict__ Bt,
    const float* __restrict__ bias, void* __restrict__ Cout,
    ushort* __restrict__ kvp,
    int N, int K, int flags)
{
  __shared__ ushort As[128*32];
  __shared__ ushort Bs[128*32];
  const int t = threadIdx.x;
  const int bm = blockIdx.y << 7, bn = blockIdx.x << 7;
  const int lane = t & 63, wid = t >> 6;
  const int wm = (wid >> 1) << 6, wn = (wid & 1) << 6;
  const int fr = lane & 15, kg = lane >> 4;

  f32x4 acc[4][4];
#pragma unroll
  for (int i=0;i<4;++i)
#pragma unroll
    for (int j=0;j<4;++j) acc[i][j] = (f32x4){0.f,0.f,0.f,0.f};

  const int rA0 = t >> 2,        qA0 = t & 3;
  const int rA1 = (t+256) >> 2;
  const size_t aOff0 = (size_t)(bm + rA0)*K + qA0*8;
  const size_t aOff1 = (size_t)(bm + rA1)*K + qA0*8;
  const size_t bOff0 = (size_t)(bn + rA0)*K + qA0*8;
  const size_t bOff1 = (size_t)(bn + rA1)*K + qA0*8;
  const int lA0 = (rA0<<5) + ((qA0 ^ ((rA0>>1)&3))<<3);
  const int lA1 = (rA1<<5) + ((qA0 ^ ((rA1>>1)&3))<<3);

  for (int k0=0; k0<K; k0+=32){
    ushort8 va0 = *(const ushort8*)(A  + aOff0 + k0);
    ushort8 va1 = *(const ushort8*)(A  + aOff1 + k0);
    ushort8 vb0 = *(const ushort8*)(Bt + bOff0 + k0);
    ushort8 vb1 = *(const ushort8*)(Bt + bOff1 + k0);
    *(ushort8*)&As[lA0] = va0;
    *(ushort8*)&As[lA1] = va1;
    *(ushort8*)&Bs[lA0] = vb0;
    *(ushort8*)&Bs[lA1] = vb1;
    __syncthreads();
    ushort8 af[4], bfr[4];
#pragma unroll
    for (int i=0;i<4;++i){
      int ra = wm + (i<<4) + fr;
      af[i]  = *(const ushort8*)&As[(ra<<5) + ((kg ^ ((ra>>1)&3))<<3)];
      int rb = wn + (i<<4) + fr;
      bfr[i] = *(const ushort8*)&Bs[(rb<<5) + ((kg ^ ((rb>>1)&3))<<3)];
    }
#pragma unroll
    for (int i=0;i<4;++i)
#pragma unroll
      for (int j=0;j<4;++j)
        asm("v_mfma_f32_16x16x32_bf16 %0, %1, %2, %0"
            : "+v"(acc[i][j]) : "v"(af[i]), "v"(bfr[j]));
    __syncthreads();
  }

  const int colBase = bn + wn + fr;
  const int rowBase = bm + wm + (kg << 2);

  if (flags & 16){
#pragma unroll
    for (int j=0;j<4;++j){
      int col = colBase + (j<<4);
      if (col >= N) continue;               // 672 is 16-aligned: wave-uniform
      float bv = bias[col];
#pragma unroll
      for (int i=0;i<4;++i){
        int row0 = rowBase + (i<<4);
#pragma unroll
        for (int r=0;r<4;++r){
          float v = acc[i][j][r] + bv;
          float o = __shfl_xor(v, 1, 64);   // partner (t2 for even lanes)
          if ((lane & 1) == 0){
            float val = v * (1.f/(1.f+__expf(-o)));
            size_t yi = (size_t)(row0+r)*PRED + (col>>1);
            float* yp = (float*)Cout;
            yp[yi] = (flags & 32) ? (yp[yi] + val) : val;
          }
        }
      }
    }
    return;
  }

#pragma unroll
  for (int j=0;j<4;++j){
    int col = colBase + (j<<4);
    if (col >= N) continue;
    float bv = bias[col];
#pragma unroll
    for (int i=0;i<4;++i){
      int row0 = rowBase + (i<<4);
#pragma unroll
      for (int r=0;r<4;++r){
        float v = acc[i][j][r] + bv;
        if (flags & 1) v = fmaxf(v, 0.f);
        int row = row0 + r;
        size_t idx = (size_t)row*N + col;
        if (flags & 2) ((ushort*)Cout)[idx] = f2b(v);
        else if (flags & 8){
          if (col < 512) ((float*)Cout)[idx] = v;
          else {
            int hh = (col >> 6) & 7;
            int dd = col & 63;
            int bb = row / LL_; int jr = row - bb*LL_;
            ushort bfv = f2b(v);
            if (col < 1024)   // K rows: kR [bh][L][d]
              kvp[((size_t)(bb*8+hh)*LL_ + jr)*64 + dd] = bfv;
            else              // V rows: [bh][L][d]
              kvp[KVSEG + ((size_t)(bb*8+hh)*LL_ + jr)*64 + dd] = bfv;
          }
        } else {
          ((float*)Cout)[idx] = v;
        }
      }
    }
  }
}

// ---------- sampled-QK + M score: 8 lanes per sampled row, coalesced ----------
__global__ __launch_bounds__(256) void msc3_k(const float* __restrict__ qkv,
                                              const ushort* __restrict__ kR,
                                              const int* __restrict__ samp,
                                              float* __restrict__ Mb){
  __shared__ float sq[8][64];
  __shared__ int sidx[8][UK];
  __shared__ float sd[8][UK];
  int blk = blockIdx.x;          // bh*90 + l8
  int l8 = blk % 90; int bh = blk / 90;
  int b = bh >> 3, h = bh & 7; int l0 = l8*8;
  int t = threadIdx.x;
  for (int i=t; i<8*64; i+=256){
    int u = i>>6, d = i&63;
    sq[u][d] = qkv[(size_t)(b*LL_ + l0+u)*1536 + h*64 + d];
  }
  for (int i=t; i<8*UK; i+=256)
    sidx[i/UK][i%UK] = samp[(l0 + i/UK)*UK + i%UK];
  __syncthreads();
  int g = t >> 3, gl = t & 7;          // 32 groups of 8 lanes
  const ushort* kb = kR + (size_t)bh*LL_*64;
  for (int p = g; p < 8*UK; p += 32){
    int li = p / UK, u = p - li*UK;
    int j = sidx[li][u];
    ushort8 kk = *(const ushort8*)(kb + (size_t)j*64 + gl*8);   // coalesced 128B/row
    const float* qu = &sq[li][gl*8];
    float a = 0.f;
#pragma unroll
    for (int e=0;e<8;++e) a = fmaf(qu[e], b2f(kk[e]), a);
    a += __shfl_xor(a, 1, 8);
    a += __shfl_xor(a, 2, 8);
    a += __shfl_xor(a, 4, 8);
    if (gl == 0) sd[li][u] = a;
  }
  __syncthreads();
  int lane = t & 63, wid = t >> 6;
  for (int li = wid; li < 8; li += 4){
    float v  = (lane < UK) ? sd[li][lane] : -INFINITY;
    float sm = (lane < UK) ? v : 0.f;
    float mx = wredmax(v);
    sm = wredsum(sm);
    if (lane == 0) Mb[(size_t)bh*LL_ + l0 + li] = mx - sm*(1.f/LL_);
  }
}

// ---------- top-U per (b,h): one wave, shuffle-only; also builds sel map ----------
__global__ __launch_bounds__(64) void topk2_k(const float* __restrict__ Mb,
                                              int* __restrict__ mtop,
                                              int* __restrict__ sel){
  int bh = blockIdx.x; int lane = threadIdx.x;
  const float* mp = Mb + (size_t)bh*LL_;
  for (int j=lane; j<LL_; j+=64) sel[(size_t)bh*LL_ + j] = -1;
  float v[12]; int vi[12];
#pragma unroll
  for (int i=0;i<12;++i){
    int j = lane + i*64;
    bool ok = j < LL_;
    v[i] = ok ? mp[j] : -INFINITY;
    vi[i] = ok ? j : (LL_ + i);
  }
  for (int it=0; it<UK; ++it){
    float best = v[0]; int bi = vi[0]; int bslot = 0;
#pragma unroll
    for (int i=1;i<12;++i){
      if (v[i] > best || (v[i]==best && vi[i] < bi)){ best=v[i]; bi=vi[i]; bslot=i; }
    }
    float gb = best; int gi = bi;
#pragma unroll
    for (int o=32;o>0;o>>=1){
      float ov = __shfl_xor(gb,o,64); int oi = __shfl_xor(gi,o,64);
      if (ov > gb || (ov==gb && oi < gi)){ gb=ov; gi=oi; }
    }
    if (lane==0){
      mtop[(size_t)bh*UK + it] = gi;
      sel[(size_t)bh*LL_ + gi] = it;
    }
    if (bi == gi){
#pragma unroll
      for (int i=0;i<12;++i) if (i==bslot) v[i] = -INFINITY;
    }
  }
}

// ---------- combine per-chunk V sums -> v mean ----------
__global__ __launch_bounds__(256) void vmnc_k(const float* __restrict__ pvs,
                                              float* __restrict__ vmn){
  int idx = blockIdx.x*256 + threadIdx.x;   // < 64*64
  if (idx >= 64*64) return;
  int bh = idx >> 6, d = idx & 63;
  float s = 0.f;
#pragma unroll
  for (int ch=0; ch<NCH; ++ch) s += pvs[((size_t)bh*NCH + ch)*64 + d];
  vmn[idx] = s*(1.f/LL_);
}

// ---------- chunked attention partials: one block per (b,h,chunk) ----------
__global__ __launch_bounds__(256) void attn4_k(const float* __restrict__ qkv,
                                               const ushort* __restrict__ kR,
                                               const ushort* __restrict__ vp,
                                               const int* __restrict__ mtop,
                                               float* __restrict__ pacc,
                                               float* __restrict__ pm,
                                               float* __restrict__ pl,
                                               float* __restrict__ pvs){
  __shared__ ushort skT[64][TJC];    // K^T chunk
  __shared__ ushort sv[TJC][64];     // V chunk
  __shared__ float  sq[UK][64];
  __shared__ float  sc[UK][TJC];
  __shared__ float  part[4][64];
  int blk = blockIdx.x;
  int ch = blk % NCH; int bh = blk / NCH;
  int b = bh >> 3, h = bh & 7; int t0 = ch*TJC;
  int t = threadIdx.x, lane = t & 63, wid = t >> 6;
  for (int idx=t; idx<TJC*8; idx+=256){
    int jj = idx>>3, c8 = idx&7;
    ushort8 kk = *(const ushort8*)(kR + ((size_t)bh*LL_ + t0+jj)*64 + c8*8);
#pragma unroll
    for (int e=0;e<8;++e) skT[c8*8+e][jj] = kk[e];
  }
  for (int idx=t; idx<TJC*8; idx+=256){
    int jj = idx>>3, c8 = idx&7;
    *(ushort8*)&sv[jj][c8*8] =
      *(const ushort8*)(vp + ((size_t)bh*LL_ + t0+jj)*64 + c8*8);
  }
  for (int idx=t; idx<UK*64; idx+=256){
    int u = idx>>6, d = idx&63;
    int row = mtop[bh*UK + u];
    sq[u][d] = qkv[(size_t)(b*LL_ + row)*1536 + h*64 + d];
  }
  __syncthreads();
  {
    int d = t & 63, q = t >> 6;
    float s = 0.f;
    for (int jj=q; jj<TJC; jj+=4) s += b2f(sv[jj][d]);
    part[q][d] = s;
  }
  for (int idx=t; idx<UK*(TJC/8); idx+=256){
    int u = idx/(TJC/8), jb = idx%(TJC/8);
    float dot[8] = {0.f,0.f,0.f,0.f,0.f,0.f,0.f,0.f};
    const float* qu = sq[u];
#pragma unroll
    for (int d=0; d<64; ++d){
      ushort8 kk = *(const ushort8*)&skT[d][jb*8];
      float qv = qu[d];
#pragma unroll
      for (int e=0;e<8;++e) dot[e] = fmaf(qv, b2f(kk[e]), dot[e]);
    }
#pragma unroll
    for (int e=0;e<8;++e) sc[u][jb*8+e] = dot[e]*0.125f;
  }
  __syncthreads();
  if (t < 64)
    pvs[((size_t)bh*NCH + ch)*64 + t] = part[0][t]+part[1][t]+part[2][t]+part[3][t];
  for (int u=wid; u<UK; u+=4){
    float v0 = sc[u][lane];
    float v1 = (lane < TJC-64) ? sc[u][64+lane] : -3.0e38f;
    float mx = wredmax(fmaxf(v0,v1));
    float e0 = __expf(v0-mx);
    float e1 = (lane < TJC-64) ? __expf(v1-mx) : 0.f;
    sc[u][lane] = e0;
    if (lane < TJC-64) sc[u][64+lane] = e1;
    float s = wredsum(e0+e1);
    if (lane==0){
      pm[((size_t)bh*NCH+ch)*UK + u] = mx;
      pl[((size_t)bh*NCH+ch)*UK + u] = s;
    }
  }
  __syncthreads();
  for (int idx=t; idx<UK*64; idx+=256){
    int u = idx>>6, d = idx&63;
    const float* scu = sc[u];
    float a = 0.f;
#pragma unroll 8
    for (int jj=0; jj<TJC; ++jj) a = fmaf(scu[jj], b2f(sv[jj][d]), a);
    pacc[(((size_t)bh*NCH+ch)*UK + u)*64 + d] = a;
  }
}

// ---------- write ctx: vmean broadcast or combined attention row ----------
__global__ __launch_bounds__(256) void ctxw_k(const float* __restrict__ pacc,
                                              const float* __restrict__ pm,
                                              const float* __restrict__ pl,
                                              const float* __restrict__ vmn,
                                              const int* __restrict__ sel,
                                              ushort* __restrict__ ctx){
  int bl = blockIdx.x;                // b*LL_ + l
  int b = bl / LL_; int l = bl - b*LL_;
  int t = threadIdx.x;
  for (int c=t; c<DM; c+=256){
    int h = c >> 6, d = c & 63;
    int bh = b*8 + h;
    int u = sel[(size_t)bh*LL_ + l];
    float val;
    if (u < 0){
      val = vmn[bh*64 + d];
    } else {
      float pmv[NCH];
      float M = -3.0e38f;
#pragma unroll
      for (int ch=0; ch<NCH; ++ch){
        pmv[ch] = pm[((size_t)bh*NCH+ch)*UK + u];
        M = fmaxf(M, pmv[ch]);
      }
      float L = 0.f, A = 0.f;
#pragma unroll
      for (int ch=0; ch<NCH; ++ch){
        float w = __expf(pmv[ch] - M);
        L += w * pl[((size_t)bh*NCH+ch)*UK + u];
        A += w * pacc[(((size_t)bh*NCH+ch)*UK + u)*64 + d];
      }
      val = A / L;
    }
    ctx[(size_t)bl*DM + c] = f2b(val);
  }
}

// ---------- LN(a - s): bf16 a, fp32 s, single-pass, bf16 out ----------
__global__ __launch_bounds__(256) void subln_k(const ushort* __restrict__ a,
                                               const float* __restrict__ s,
                                               const float* __restrict__ g,
                                               const float* __restrict__ be,
                                               ushort* __restrict__ obf){
  __shared__ float red[8];
  int row = blockIdx.x;
  size_t base = (size_t)row * DM;
  int t = threadIdx.x;
  int lane = t & 63, wid = t >> 6;
  float e0 = b2f(a[base+t])     - s[base+t];
  float e1 = b2f(a[base+t+256]) - s[base+t+256];
  float s1 = e0+e1;
  float s2 = e0*e0 + e1*e1;
#pragma unroll
  for (int o=32;o>0;o>>=1){
    s1 += __shfl_xor(s1,o,64);
    s2 += __shfl_xor(s2,o,64);
  }
  if (lane==0){ red[wid]=s1; red[4+wid]=s2; }
  __syncthreads();
  float S = red[0]+red[1]+red[2]+red[3];
  float Q = red[4]+red[5]+red[6]+red[7];
  float mu = S*(1.f/DM);
  float var = fmaxf(Q*(1.f/DM) - mu*mu, 0.f);
  float rs = rsqrtf(var + EPSF);
  obf[base+t]     = f2b((e0-mu)*rs*g[t]     + be[t]);
  obf[base+t+256] = f2b((e1-mu)*rs*g[t+256] + be[t+256]);
}

// ---------- final: LDS-tiled transpose, out[b,p,n] = y[b,n,p]*std + mean ----------
__global__ __launch_bounds__(256) void final2_k(const float* __restrict__ y,
                                                const float* __restrict__ stdv,
                                                const float* __restrict__ mean,
                                                float* __restrict__ out){
  __shared__ float tile[32][33];
  int n0 = blockIdx.x*32, p0 = blockIdx.y*32, b = blockIdx.z;
  int tx = threadIdx.x & 31, ty = threadIdx.x >> 5;
  for (int i=ty; i<32; i+=8){
    int n = n0+i, p = p0+tx;
    tile[i][tx] = (n<NF && p<PRED) ? y[((size_t)b*LL_+n)*PRED + p] : 0.f;
  }
  __syncthreads();
  for (int i=ty; i<32; i+=8){
    int p = p0+i, n = n0+tx;
    if (p<PRED && n<NF)
      out[((size_t)b*PRED + p)*NF + n] = tile[tx][i]*stdv[b*NF+n] + mean[b*NF+n];
  }
}

// ---------------- host ----------------
extern "C" void kernel_launch(void* const* d_in, const int* in_sizes, int n_in,
                              void* d_out, int out_size, void* d_ws, size_t ws_size,
                              hipStream_t stream){
  const float* x_enc = (const float*)d_in[0];
  const int*   samp  = (const int*)  d_in[1];
  const float* embw  = (const float*)d_in[2];
  const float* embb  = (const float*)d_in[3];
  const float* wq    = (const float*)d_in[4];
  const float* bq    = (const float*)d_in[5];
  const float* wk    = (const float*)d_in[6];
  const float* bk    = (const float*)d_in[7];
  const float* wv    = (const float*)d_in[8];
  const float* bv    = (const float*)d_in[9];
  const float* wo    = (const float*)d_in[10];
  const float* bo    = (const float*)d_in[11];
  const float* ln1g  = (const float*)d_in[12];
  const float* ln1b  = (const float*)d_in[13];
  const float* w1    = (const float*)d_in[14];
  const float* b1    = (const float*)d_in[15];
  const float* w2    = (const float*)d_in[16];
  const float* b2    = (const float*)d_in[17];
  const float* ln2g  = (const float*)d_in[18];
  const float* ln2b  = (const float*)d_in[19];
  const float* wout  = (const float*)d_in[20];
  const float* boutp = (const float*)d_in[21];
  const float* wg    = (const float*)d_in[22];
  const float* bg    = (const float*)d_in[23];
  float* out = (float*)d_out;

  char* wsb = (char*)d_ws;
  size_t off = 0;
  auto alloc = [&](size_t bytes)->void*{
    void* p = wsb + off; off += (bytes + 255) & ~(size_t)255; return p;
  };
  float* mean  = (float*)alloc((size_t)BB_*NF*4);
  float* stdv  = (float*)alloc((size_t)BB_*NF*4);
  float* rstd  = (float*)alloc((size_t)BB_*NF*4);
  float* pp    = (float*)alloc((size_t)BB_*6*NLC*128*4);
  float* bqkv  = (float*)alloc(2*1536*4);
  float* bog   = (float*)alloc(2*672*4);
  ushort* xn     = (ushort*)alloc((size_t)BL*KPE*2);
  ushort* we_t   = (ushort*)alloc((size_t)512*KPE*2);
  ushort* wqkv_t = (ushort*)alloc((size_t)2*1536*512*2);
  ushort* wo_t   = (ushort*)alloc((size_t)2*512*512*2);
  ushort* w1_t   = (ushort*)alloc((size_t)2*128*512*2);
  ushort* w2_t   = (ushort*)alloc((size_t)2*512*128*2);
  ushort* wog_t  = (ushort*)alloc((size_t)2*768*512*2);
  ushort* h_bf   = (ushort*)alloc((size_t)BL*DM*2);
  ushort* hx_bf  = (ushort*)alloc((size_t)BL*DM*2);
  ushort* ctx_bf = (ushort*)alloc((size_t)BL*DM*2);
  ushort* ff1_bf = (ushort*)alloc((size_t)BL*DFF*2);
  ushort* kvpack = (ushort*)alloc(2*KVSEG*2);
  float* qkv = (float*)alloc((size_t)BL*1536*4);
  float* tmp = (float*)alloc((size_t)BL*DM*4);
  float* y   = (float*)alloc((size_t)BL*PRED*4);
  float* Mb  = (float*)alloc((size_t)BB_*HH_*LL_*4);
  int*  mtop = (int*)  alloc((size_t)BB_*HH_*UK*4);
  int*  sel  = (int*)  alloc((size_t)BB_*HH_*LL_*4);
  float* vmn = (float*)alloc((size_t)BB_*HH_*DH*4);
  float* pacc = (float*)alloc((size_t)64*NCH*UK*64*4);
  float* pm   = (float*)alloc((size_t)64*NCH*UK*4);
  float* pl   = (float*)alloc((size_t)64*NCH*UK*4);
  float* pvs  = (float*)alloc((size_t)64*NCH*64*4);
  if (off > ws_size) return;
  ushort* kRp   = kvpack;
  ushort* vpack = kvpack + KVSEG;

  stats3_k<<<BB_*6*NLC, 256, 0, stream>>>(x_enc, pp);
  statsc_k<<<BB_*6, 64, 0, stream>>>(pp, mean, stdv, rstd);
  xnorm_k<<<(BL*KPE+255)/256, 256, 0, stream>>>(x_enc, mean, rstd, xn);

  TPack tp; int blk = 0; int di = 0;
  auto addT = [&](const float* in, ushort* o, int N, int K, int Npad, int Kpad, int ilv){
    TDesc& d = tp.d[di++]; d.in=in; d.out=o; d.N=N; d.K=K; d.Npad=Npad; d.Kpad=Kpad; d.ilv=ilv;
    d.nbx = (Kpad+31)/32; d.blk0 = blk; blk += d.nbx * ((Npad+31)/32);
  };
  addT(embw, we_t, 512, NF, 512, KPE, 0);
  for (int l=0;l<NLAY;++l){
    addT(wq + (size_t)l*262144, wqkv_t + (size_t)l*786432,            512,512,512,512,0);
    addT(wk + (size_t)l*262144, wqkv_t + (size_t)l*786432 + 262144,   512,512,512,512,0);
    addT(wv + (size_t)l*262144, wqkv_t + (size_t)l*786432 + 524288,   512,512,512,512,0);
    addT(wo + (size_t)l*262144, wo_t   + (size_t)l*262144,            512,512,512,512,0);
    addT(w1 + (size_t)l*65536,  w1_t   + (size_t)l*65536,             128,512,128,512,0);
    addT(w2 + (size_t)l*65536,  w2_t   + (size_t)l*65536,             512,128,512,128,0);
    addT(wout + (size_t)l*172032, wog_t + (size_t)l*393216,           336,512,384,512,1);
    addT(wg   + (size_t)l*172032, wog_t + (size_t)l*393216,           336,512,384,512,2);
  }
  tp.n = di;
  transpose_k<<<blk, 256, 0, stream>>>(tp);
  pack_bias_k<<<12, 256, 0, stream>>>(bq, bk, bv, boutp, bg, bqkv, bog);

  // embed: h = xn @ embw + embb  (bf16 out)
  gemm_k<<<dim3(4,45), 256, 0, stream>>>(xn, we_t, embb, h_bf, nullptr,
                                         512, KPE, 2);

  for (int l=0;l<NLAY;++l){
    gemm_k<<<dim3(12,45), 256, 0, stream>>>(h_bf, wqkv_t + (size_t)l*786432,
                                            bqkv + l*1536, qkv, kvpack,
                                            1536, 512, 8);
    msc3_k<<<64*90, 256, 0, stream>>>(qkv, kRp, samp, Mb);
    topk2_k<<<BB_*HH_, 64, 0, stream>>>(Mb, mtop, sel);
    attn4_k<<<64*NCH, 256, 0, stream>>>(qkv, kRp, vpack, mtop, pacc, pm, pl, pvs);
    vmnc_k<<<16, 256, 0, stream>>>(pvs, vmn);
    ctxw_k<<<BL, 256, 0, stream>>>(pacc, pm, pl, vmn, sel, ctx_bf);
    gemm_k<<<dim3(4,45), 256, 0, stream>>>(ctx_bf, wo_t + (size_t)l*262144,
                                           bo + l*512, tmp, nullptr,
                                           512, 512, 0);
    subln_k<<<BL, 256, 0, stream>>>(h_bf, tmp, ln1g + l*512, ln1b + l*512, hx_bf);
    gemm_k<<<dim3(1,45), 256, 0, stream>>>(hx_bf, w1_t + (size_t)l*65536,
                                           b1 + l*128, ff1_bf, nullptr,
                                           128, 512, 3);
    gemm_k<<<dim3(4,45), 256, 0, stream>>>(ff1_bf, w2_t + (size_t)l*65536,
                                           b2 + l*512, tmp, nullptr,
                                           512, 128, 0);
    subln_k<<<BL, 256, 0, stream>>>(hx_bf, tmp, ln2g + l*512, ln2b + l*512, h_bf);
    gemm_k<<<dim3(6,45), 256, 0, stream>>>(h_bf, wog_t + (size_t)l*393216,
                                           bog + l*672, y, nullptr,
                                           672, 512, 16 | (l ? 32 : 0));
  }
  final2_k<<<dim3((NF+31)/32,(PRED+31)/32,BB_), 256, 0, stream>>>(y, stdv, mean, out);
}